// Round 13
// baseline (79.655 us; speedup 1.0000x reference)
//
#include <hip/hip_runtime.h>

#define NUM_BINS 15
#define NCOLS 200
#define BLOCK 256
#define LANES_PER_ROW 8            // octet per row
#define ROWS_PER_BLOCK_ITER (BLOCK / LANES_PER_ROW)   // 32
#define GRID 1024                  // 4 blocks/CU — best measured (R10: 79.3us; 1536 was 80.3)
#define FBLOCK 1024                // final kernel: 16 waves, one per bin (15 used)

__device__ __forceinline__ float max4(float4 q) {
    return fmaxf(fmaxf(q.x, q.y), fmaxf(q.z, q.w));
}
__device__ __forceinline__ float exp4sum(float4 q, float m) {
    return __expf(q.x - m) + __expf(q.y - m) + __expf(q.z - m) + __expf(q.w - m);
}

// R10-verbatim (best measured: 79.3 us total, ~5.45 TB/s main loop).
// Octet-per-row direct-to-register streaming; unconditional slot-store flush
// (poison-immune -> no memset dispatch); latency-parallel final reduce.
__global__ __launch_bounds__(BLOCK) void ece_main_kernel(
    const float* __restrict__ logits,
    const int* __restrict__ targs,
    float* __restrict__ g_conf,       // [NUM_BINS][GRID] slots
    unsigned int* __restrict__ g_cnt, // [NUM_BINS][GRID]
    unsigned int* __restrict__ g_acc, // [NUM_BINS][GRID]
    int N)
{
    __shared__ float s_conf[NUM_BINS];
    __shared__ unsigned int s_cnt[NUM_BINS];
    __shared__ unsigned int s_acc[NUM_BINS];

    const int t = threadIdx.x;
    if (t < NUM_BINS) { s_conf[t] = 0.0f; s_cnt[t] = 0u; s_acc[t] = 0u; }
    __syncthreads();

    const int lrow = t >> 3;          // 0..31: row within block-iteration
    const int sub = t & 7;            // lane within octet
    const int stride = GRID * ROWS_PER_BLOCK_ITER;   // compile-time 32768

    int row = blockIdx.x * ROWS_PER_BLOCK_ITER + lrow;

    // prefetch first iteration's target index (breaks targ->logit load chain)
    int tg = 0;
    if (sub == 0 && row < N) tg = targs[row];

    for (; row < N; row += stride) {
        const float* rp = logits + (size_t)row * NCOLS + sub * 4;

        // 6 full f4 loads (f4 0..47) + 1 partial (f4 48,49 on sub<2).
        float4 q0 = *reinterpret_cast<const float4*>(rp);
        float4 q1 = *reinterpret_cast<const float4*>(rp + 32);
        float4 q2 = *reinterpret_cast<const float4*>(rp + 64);
        float4 q3 = *reinterpret_cast<const float4*>(rp + 96);
        float4 q4 = *reinterpret_cast<const float4*>(rp + 128);
        float4 q5 = *reinterpret_cast<const float4*>(rp + 160);
        const bool has7 = (sub < 2);
        float4 q6 = make_float4(-INFINITY, -INFINITY, -INFINITY, -INFINITY);
        if (has7) q6 = *reinterpret_cast<const float4*>(rp + 192);  // f4 48+sub

        // target logit for THIS row (tg prefetched) + next row's target index
        float tl = 0.0f;
        int tg_next = 0;
        if (sub == 0) {
            tl = logits[(size_t)row * NCOLS + tg];
            int rn = row + stride;
            if (rn < N) tg_next = targs[rn];
        }

        // per-lane max, then exact octet max (xor 1,2,4 stays in the octet)
        float m = fmaxf(fmaxf(max4(q0), max4(q1)),
                        fmaxf(fmaxf(max4(q2), max4(q3)),
                              fmaxf(max4(q4), max4(q5))));
        if (has7) m = fmaxf(m, max4(q6));
        m = fmaxf(m, __shfl_xor(m, 1));
        m = fmaxf(m, __shfl_xor(m, 2));
        m = fmaxf(m, __shfl_xor(m, 4));

        // sum of exp(x - rowmax)
        float s = exp4sum(q0, m) + exp4sum(q1, m) + exp4sum(q2, m)
                + exp4sum(q3, m) + exp4sum(q4, m) + exp4sum(q5, m);
        if (has7) s += exp4sum(q6, m);
        s += __shfl_xor(s, 1);
        s += __shfl_xor(s, 2);
        s += __shfl_xor(s, 4);

        if (sub == 0) {
            float conf = 1.0f / s;                            // max softmax prob
            int b = (int)ceilf(conf * (float)NUM_BINS) - 1;   // torch (lo, hi] bins
            b = min(max(b, 0), NUM_BINS - 1);
            atomicAdd(&s_conf[b], conf);
            atomicAdd(&s_cnt[b], 1u);
            if (tl == m) atomicAdd(&s_acc[b], 1u);            // pred == targ
        }
        tg = tg_next;
    }

    __syncthreads();
    if (t < NUM_BINS) {   // unconditional slot stores: poison-immune, no memset
        g_conf[t * GRID + blockIdx.x] = s_conf[t];
        g_cnt[t * GRID + blockIdx.x] = s_cnt[t];
        g_acc[t * GRID + blockIdx.x] = s_acc[t];
    }
}

// Final reduction, latency-parallel: one wave per bin; lane k sums slots
// {k, k+64, ...} with a compile-time-unrolled loop of independent coalesced
// loads, then a 6-step wave reduce.
__global__ __launch_bounds__(FBLOCK) void ece_final_kernel(
    const float* __restrict__ g_conf,
    const unsigned int* __restrict__ g_cnt,
    const unsigned int* __restrict__ g_acc,
    float* __restrict__ out, int N)
{
    __shared__ double s_term[NUM_BINS];
    const int t = threadIdx.x;
    const int b = t >> 6;             // wave id = bin (15 active, wave 15 idle)
    const int k = t & 63;

    if (b < NUM_BINS) {
        double conf = 0.0;
        unsigned int cnt = 0u, acc = 0u;
        #pragma unroll
        for (int j = 0; j < GRID / 64; ++j) {      // 16 independent loads each
            const int blk = k + 64 * j;
            conf += (double)g_conf[b * GRID + blk];
            cnt  += g_cnt[b * GRID + blk];
            acc  += g_acc[b * GRID + blk];
        }
        #pragma unroll
        for (int off = 1; off <= 32; off <<= 1) {  // 64-lane reduce
            conf += __shfl_xor(conf, off);
            cnt  += __shfl_xor(cnt, off);
            acc  += __shfl_xor(acc, off);
        }
        if (k == 0) {
            double term = 0.0;
            if (cnt > 0u) {
                double dc = (double)cnt;
                term = fabs(conf / dc - (double)acc / dc) * (dc / (double)N);
            }
            s_term[b] = term;
        }
    }
    __syncthreads();
    if (t == 0) {
        double e = 0.0;
        #pragma unroll
        for (int b2 = 0; b2 < NUM_BINS; ++b2) e += s_term[b2];
        out[0] = (float)e;
    }
}

extern "C" void kernel_launch(void* const* d_in, const int* in_sizes, int n_in,
                              void* d_out, int out_size, void* d_ws, size_t ws_size,
                              hipStream_t stream) {
    const float* logits = (const float*)d_in[0];
    const int* targs = (const int*)d_in[1];   // jax int64 -> int32 on device
    int N = in_sizes[1];                      // 524288 rows
    float* out = (float*)d_out;

    // slot workspace: [15][GRID] x {float, u32, u32} = 184320 B
    float* g_conf = (float*)d_ws;
    unsigned int* g_cnt = (unsigned int*)(g_conf + NUM_BINS * GRID);
    unsigned int* g_acc = g_cnt + NUM_BINS * GRID;

    const int total_groups = (N + ROWS_PER_BLOCK_ITER - 1) / ROWS_PER_BLOCK_ITER;
    const int grid = min(total_groups, GRID);   // 1024 for N=524288

    // If grid < GRID, unwritten slots would hold poison -> zero them first.
    if (grid < GRID) {
        hipMemsetAsync(d_ws, 0, (size_t)NUM_BINS * GRID * 12, stream);
    }

    ece_main_kernel<<<grid, BLOCK, 0, stream>>>(logits, targs, g_conf,
                                                g_cnt, g_acc, N);
    ece_final_kernel<<<1, FBLOCK, 0, stream>>>(g_conf, g_cnt, g_acc, out, N);
}

// Round 14
// 79.429 us; speedup vs baseline: 1.0028x; 1.0028x over previous
//
#include <hip/hip_runtime.h>

#define NUM_BINS 15
#define NCOLS 200
#define BLOCK 256
#define LANES_PER_ROW 8            // octet per row
#define ROWS_PER_BLOCK_ITER (BLOCK / LANES_PER_ROW)   // 32
#define GRID 1024                  // 4 blocks/CU — best measured (R10: 79.3us; 1536 was 80.3)
#define FBLOCK 1024                // final kernel: 16 waves, one per bin (15 used)

__device__ __forceinline__ float max4(float4 q) {
    return fmaxf(fmaxf(q.x, q.y), fmaxf(q.z, q.w));
}
__device__ __forceinline__ float exp4sum(float4 q, float m) {
    return __expf(q.x - m) + __expf(q.y - m) + __expf(q.z - m) + __expf(q.w - m);
}

// R10-verbatim (best measured: 79.3 us total, ~5.45 TB/s main loop).
// Octet-per-row direct-to-register streaming; unconditional slot-store flush
// (poison-immune -> no memset dispatch); latency-parallel final reduce.
__global__ __launch_bounds__(BLOCK) void ece_main_kernel(
    const float* __restrict__ logits,
    const int* __restrict__ targs,
    float* __restrict__ g_conf,       // [NUM_BINS][GRID] slots
    unsigned int* __restrict__ g_cnt, // [NUM_BINS][GRID]
    unsigned int* __restrict__ g_acc, // [NUM_BINS][GRID]
    int N)
{
    __shared__ float s_conf[NUM_BINS];
    __shared__ unsigned int s_cnt[NUM_BINS];
    __shared__ unsigned int s_acc[NUM_BINS];

    const int t = threadIdx.x;
    if (t < NUM_BINS) { s_conf[t] = 0.0f; s_cnt[t] = 0u; s_acc[t] = 0u; }
    __syncthreads();

    const int lrow = t >> 3;          // 0..31: row within block-iteration
    const int sub = t & 7;            // lane within octet
    const int stride = GRID * ROWS_PER_BLOCK_ITER;   // compile-time 32768

    int row = blockIdx.x * ROWS_PER_BLOCK_ITER + lrow;

    // prefetch first iteration's target index (breaks targ->logit load chain)
    int tg = 0;
    if (sub == 0 && row < N) tg = targs[row];

    for (; row < N; row += stride) {
        const float* rp = logits + (size_t)row * NCOLS + sub * 4;

        // 6 full f4 loads (f4 0..47) + 1 partial (f4 48,49 on sub<2).
        float4 q0 = *reinterpret_cast<const float4*>(rp);
        float4 q1 = *reinterpret_cast<const float4*>(rp + 32);
        float4 q2 = *reinterpret_cast<const float4*>(rp + 64);
        float4 q3 = *reinterpret_cast<const float4*>(rp + 96);
        float4 q4 = *reinterpret_cast<const float4*>(rp + 128);
        float4 q5 = *reinterpret_cast<const float4*>(rp + 160);
        const bool has7 = (sub < 2);
        float4 q6 = make_float4(-INFINITY, -INFINITY, -INFINITY, -INFINITY);
        if (has7) q6 = *reinterpret_cast<const float4*>(rp + 192);  // f4 48+sub

        // target logit for THIS row (tg prefetched) + next row's target index
        float tl = 0.0f;
        int tg_next = 0;
        if (sub == 0) {
            tl = logits[(size_t)row * NCOLS + tg];
            int rn = row + stride;
            if (rn < N) tg_next = targs[rn];
        }

        // per-lane max, then exact octet max (xor 1,2,4 stays in the octet)
        float m = fmaxf(fmaxf(max4(q0), max4(q1)),
                        fmaxf(fmaxf(max4(q2), max4(q3)),
                              fmaxf(max4(q4), max4(q5))));
        if (has7) m = fmaxf(m, max4(q6));
        m = fmaxf(m, __shfl_xor(m, 1));
        m = fmaxf(m, __shfl_xor(m, 2));
        m = fmaxf(m, __shfl_xor(m, 4));

        // sum of exp(x - rowmax)
        float s = exp4sum(q0, m) + exp4sum(q1, m) + exp4sum(q2, m)
                + exp4sum(q3, m) + exp4sum(q4, m) + exp4sum(q5, m);
        if (has7) s += exp4sum(q6, m);
        s += __shfl_xor(s, 1);
        s += __shfl_xor(s, 2);
        s += __shfl_xor(s, 4);

        if (sub == 0) {
            float conf = 1.0f / s;                            // max softmax prob
            int b = (int)ceilf(conf * (float)NUM_BINS) - 1;   // torch (lo, hi] bins
            b = min(max(b, 0), NUM_BINS - 1);
            atomicAdd(&s_conf[b], conf);
            atomicAdd(&s_cnt[b], 1u);
            if (tl == m) atomicAdd(&s_acc[b], 1u);            // pred == targ
        }
        tg = tg_next;
    }

    __syncthreads();
    if (t < NUM_BINS) {   // unconditional slot stores: poison-immune, no memset
        g_conf[t * GRID + blockIdx.x] = s_conf[t];
        g_cnt[t * GRID + blockIdx.x] = s_cnt[t];
        g_acc[t * GRID + blockIdx.x] = s_acc[t];
    }
}

// Final reduction, latency-parallel: one wave per bin; lane k sums slots
// {k, k+64, ...} with a compile-time-unrolled loop of independent coalesced
// loads, then a 6-step wave reduce.
__global__ __launch_bounds__(FBLOCK) void ece_final_kernel(
    const float* __restrict__ g_conf,
    const unsigned int* __restrict__ g_cnt,
    const unsigned int* __restrict__ g_acc,
    float* __restrict__ out, int N)
{
    __shared__ double s_term[NUM_BINS];
    const int t = threadIdx.x;
    const int b = t >> 6;             // wave id = bin (15 active, wave 15 idle)
    const int k = t & 63;

    if (b < NUM_BINS) {
        double conf = 0.0;
        unsigned int cnt = 0u, acc = 0u;
        #pragma unroll
        for (int j = 0; j < GRID / 64; ++j) {      // 16 independent loads each
            const int blk = k + 64 * j;
            conf += (double)g_conf[b * GRID + blk];
            cnt  += g_cnt[b * GRID + blk];
            acc  += g_acc[b * GRID + blk];
        }
        #pragma unroll
        for (int off = 1; off <= 32; off <<= 1) {  // 64-lane reduce
            conf += __shfl_xor(conf, off);
            cnt  += __shfl_xor(cnt, off);
            acc  += __shfl_xor(acc, off);
        }
        if (k == 0) {
            double term = 0.0;
            if (cnt > 0u) {
                double dc = (double)cnt;
                term = fabs(conf / dc - (double)acc / dc) * (dc / (double)N);
            }
            s_term[b] = term;
        }
    }
    __syncthreads();
    if (t == 0) {
        double e = 0.0;
        #pragma unroll
        for (int b2 = 0; b2 < NUM_BINS; ++b2) e += s_term[b2];
        out[0] = (float)e;
    }
}

extern "C" void kernel_launch(void* const* d_in, const int* in_sizes, int n_in,
                              void* d_out, int out_size, void* d_ws, size_t ws_size,
                              hipStream_t stream) {
    const float* logits = (const float*)d_in[0];
    const int* targs = (const int*)d_in[1];   // jax int64 -> int32 on device
    int N = in_sizes[1];                      // 524288 rows
    float* out = (float*)d_out;

    // slot workspace: [15][GRID] x {float, u32, u32} = 184320 B
    float* g_conf = (float*)d_ws;
    unsigned int* g_cnt = (unsigned int*)(g_conf + NUM_BINS * GRID);
    unsigned int* g_acc = g_cnt + NUM_BINS * GRID;

    const int total_groups = (N + ROWS_PER_BLOCK_ITER - 1) / ROWS_PER_BLOCK_ITER;
    const int grid = min(total_groups, GRID);   // 1024 for N=524288

    // If grid < GRID, unwritten slots would hold poison -> zero them first.
    if (grid < GRID) {
        hipMemsetAsync(d_ws, 0, (size_t)NUM_BINS * GRID * 12, stream);
    }

    ece_main_kernel<<<grid, BLOCK, 0, stream>>>(logits, targs, g_conf,
                                                g_cnt, g_acc, N);
    ece_final_kernel<<<1, FBLOCK, 0, stream>>>(g_conf, g_cnt, g_acc, out, N);
}